// Round 14
// baseline (91.344 us; speedup 1.0000x reference)
//
#include <hip/hip_runtime.h>

// Problem constants
#define NBATCH 8
#define NLQ    256
#define NLK    1024
#define NDQ    512
#define NDV    512
#define NH     128
#define NEGV   -1000000.0f
#define TANH_SCALE 2.8853900817779268f   // 2*log2(e)
#define LOG2E      1.4426950408889634f

using f16x8 = __attribute__((ext_vector_type(8))) _Float16;
using f16x4 = __attribute__((ext_vector_type(4))) _Float16;
using f16x2 = __attribute__((ext_vector_type(2))) _Float16;
using f32x4 = __attribute__((ext_vector_type(4))) float;

__device__ __forceinline__ float fast_exp2(float x) {
#if __has_builtin(__builtin_amdgcn_exp2f)
  return __builtin_amdgcn_exp2f(x);
#else
  return exp2f(x);
#endif
}
__device__ __forceinline__ float fast_rcp(float x) {
#if __has_builtin(__builtin_amdgcn_rcpf)
  return __builtin_amdgcn_rcpf(x);
#else
  return 1.0f / x;
#endif
}

// ---------------------------------------------------------------------------
// Prep: WT fp16 [2][128][512]; WT[s][n][k] = W_s[k][n]. 256 KB, L2-resident.
// ---------------------------------------------------------------------------
__global__ __launch_bounds__(256)
void prep_wT_kernel(const float* __restrict__ Wq, const float* __restrict__ Wk,
                    _Float16* __restrict__ wT) {
  const int idx = blockIdx.x * 256 + threadIdx.x;   // 0 .. 2*512*128-1
  const int n = idx & 127;
  const int k = (idx >> 7) & 511;
  const int s = idx >> 16;
  const float* W = s ? Wk : Wq;
  wT[((size_t)(s * NH + n)) * NDQ + k] = (_Float16)W[k * NH + n];
}

// ---------------------------------------------------------------------------
// Projections via fp16 MFMA, LDS-FREE, barrier-free.
// Wave = 16 rows x 32 cols (2 frags of 16x16), block = 4 waves (64 rows).
// Grid (160, 4): bx<32 -> Q (M=2048), else K (M=8192); by = n-quarter.
// Epilogue: exp2(acc*2log2e); Q -> Eq row-major, K -> EkT[b][h][key].
// ---------------------------------------------------------------------------
__global__ __launch_bounds__(256)
void proj_mfma_kernel(const float* __restrict__ Q, const float* __restrict__ Kin,
                      const _Float16* __restrict__ wT,
                      float* __restrict__ qp, float* __restrict__ ekT) {
  const int bx = blockIdx.x;
  const int nq = blockIdx.y;          // n-quarter: cols nq*32 .. nq*32+31
  const bool isQ = (bx < 32);
  const float* A = isQ ? Q : Kin;
  const int m0 = (isQ ? bx : bx - 32) * 64;
  const int sIdx = isQ ? 0 : 1;

  const int w = threadIdx.x >> 6, lane = threadIdx.x & 63;
  const int mrow = m0 + w * 16 + (lane & 15);
  const int kseg = (lane >> 4) * 8;

  const float* aBase = A + (size_t)mrow * NDQ + kseg;
  const _Float16* wt0 = wT + ((size_t)(sIdx * NH + nq * 32 +      (lane & 15))) * NDQ + kseg;
  const _Float16* wt1 = wT + ((size_t)(sIdx * NH + nq * 32 + 16 + (lane & 15))) * NDQ + kseg;

  f32x4 acc0 = {}, acc1 = {};
#pragma unroll 4
  for (int k0 = 0; k0 < NDQ; k0 += 32) {
    const float4 a0 = *(const float4*)&aBase[k0];
    const float4 a1 = *(const float4*)&aBase[k0 + 4];
    f16x8 af;
    af[0] = (_Float16)a0.x; af[1] = (_Float16)a0.y;
    af[2] = (_Float16)a0.z; af[3] = (_Float16)a0.w;
    af[4] = (_Float16)a1.x; af[5] = (_Float16)a1.y;
    af[6] = (_Float16)a1.z; af[7] = (_Float16)a1.w;
    const f16x8 b0 = *(const f16x8*)&wt0[k0];
    const f16x8 b1 = *(const f16x8*)&wt1[k0];
    acc0 = __builtin_amdgcn_mfma_f32_16x16x32_f16(af, b0, acc0, 0, 0, 0);
    acc1 = __builtin_amdgcn_mfma_f32_16x16x32_f16(af, b1, acc1, 0, 0, 0);
  }

  const int orow = m0 + w * 16 + (lane >> 4) * 4;   // + r
  const int col0 = nq * 32 + (lane & 15);           // frag0 col; frag1 = +16
  if (isQ) {
#pragma unroll
    for (int r = 0; r < 4; ++r) {
      qp[(size_t)(orow + r) * NH + col0]      = fast_exp2(acc0[r] * TANH_SCALE);
      qp[(size_t)(orow + r) * NH + col0 + 16] = fast_exp2(acc1[r] * TANH_SCALE);
    }
  } else {
#pragma unroll
    for (int r = 0; r < 4; ++r) {
      const int grow = orow + r;
      const int b = grow >> 10, key = grow & 1023;
      ekT[((size_t)(b * NH) + col0)      * NLK + key] = fast_exp2(acc0[r] * TANH_SCALE);
      ekT[((size_t)(b * NH) + col0 + 16) * NLK + key] = fast_exp2(acc1[r] * TANH_SCALE);
    }
  }
}

// ---------------------------------------------------------------------------
// FUSED scores + masked softmax -> fp16 attn, v14.
// QR=2 (grid 8x128 = 1024 blocks = 4 blocks/CU = 32 waves/CU) + explicit
// kv double-buffer: g+1's four float2 loads issue BEFORE g's math (T14).
// Lane owns keys key0 = w*128 + 2*lane (coalesced float2 from EkT[b][h][key]);
// Eq rows + w_v wave-uniform -> scalar loads. Block = 8 waves = all 1024
// keys; softmax in-block via LDS cross-wave reduce. blockIdx.x = batch ->
// linear%8 XCD pin (EkT slice L2-resident).
//   score = Wsum - 2*sum_h w*rcp(1 + Eq*Ek); Wsum cancels in softmax.
// ---------------------------------------------------------------------------
__global__ __launch_bounds__(512)
void scores_softmax_kernel(const float* __restrict__ qp, const float* __restrict__ ekT,
                           const float* __restrict__ wv, const int* __restrict__ vlen,
                           _Float16* __restrict__ attnH) {
  const int b  = blockIdx.x;            // batch -> XCD pin (grid.x == 8)
  const int qg = blockIdx.y;            // q group (2 rows), 0..127
  const int w = threadIdx.x >> 6;       // 0..7 -> key segment of 128
  const int lane = threadIdx.x & 63;
  const int key0 = w * 128 + lane * 2;

  __shared__ float redm[8][2];
  __shared__ float reds[8][2];

  const float* kcol  = &ekT[(size_t)b * NH * NLK + key0];       // + h*NLK
  const float* qbase = &qp[(size_t)(b * NLQ + qg * 2) * NH];

  // prologue: prefetch g=0's kv
  float2 kv[4];
#pragma unroll
  for (int hh = 0; hh < 4; ++hh)
    kv[hh] = *(const float2*)&kcol[(size_t)hh * NLK];

  float2 acc0 = {}, acc1 = {};
#pragma unroll
  for (int g = 0; g < 32; ++g) {
    // prefetch NEXT g's kv while this g's math runs
    float2 kvn[4];
    if (g < 31) {
#pragma unroll
      for (int hh = 0; hh < 4; ++hh)
        kvn[hh] = *(const float2*)&kcol[(size_t)((g + 1) * 4 + hh) * NLK];
    }
    const float4 w4 = *(const float4*)&wv[g * 4];               // uniform
    const float4 qa = *(const float4*)&qbase[g * 4];            // uniform
    const float4 qb = *(const float4*)&qbase[NH + g * 4];       // uniform

    acc0.x = fmaf(w4.x, fast_rcp(fmaf(qa.x, kv[0].x, 1.0f)), acc0.x);
    acc0.y = fmaf(w4.x, fast_rcp(fmaf(qa.x, kv[0].y, 1.0f)), acc0.y);
    acc1.x = fmaf(w4.x, fast_rcp(fmaf(qb.x, kv[0].x, 1.0f)), acc1.x);
    acc1.y = fmaf(w4.x, fast_rcp(fmaf(qb.x, kv[0].y, 1.0f)), acc1.y);

    acc0.x = fmaf(w4.y, fast_rcp(fmaf(qa.y, kv[1].x, 1.0f)), acc0.x);
    acc0.y = fmaf(w4.y, fast_rcp(fmaf(qa.y, kv[1].y, 1.0f)), acc0.y);
    acc1.x = fmaf(w4.y, fast_rcp(fmaf(qb.y, kv[1].x, 1.0f)), acc1.x);
    acc1.y = fmaf(w4.y, fast_rcp(fmaf(qb.y, kv[1].y, 1.0f)), acc1.y);

    acc0.x = fmaf(w4.z, fast_rcp(fmaf(qa.z, kv[2].x, 1.0f)), acc0.x);
    acc0.y = fmaf(w4.z, fast_rcp(fmaf(qa.z, kv[2].y, 1.0f)), acc0.y);
    acc1.x = fmaf(w4.z, fast_rcp(fmaf(qb.z, kv[2].x, 1.0f)), acc1.x);
    acc1.y = fmaf(w4.z, fast_rcp(fmaf(qb.z, kv[2].y, 1.0f)), acc1.y);

    acc0.x = fmaf(w4.w, fast_rcp(fmaf(qa.w, kv[3].x, 1.0f)), acc0.x);
    acc0.y = fmaf(w4.w, fast_rcp(fmaf(qa.w, kv[3].y, 1.0f)), acc0.y);
    acc1.x = fmaf(w4.w, fast_rcp(fmaf(qb.w, kv[3].x, 1.0f)), acc1.x);
    acc1.y = fmaf(w4.w, fast_rcp(fmaf(qb.w, kv[3].y, 1.0f)), acc1.y);

#pragma unroll
    for (int hh = 0; hh < 4; ++hh) kv[hh] = kvn[hh];
  }

  // finalize scores with mask
  const int VL = vlen[b];
  float2 s0, s1;
  s0.x = (key0 + 0 < VL) ? -2.0f * acc0.x : NEGV;
  s0.y = (key0 + 1 < VL) ? -2.0f * acc0.y : NEGV;
  s1.x = (key0 + 0 < VL) ? -2.0f * acc1.x : NEGV;
  s1.y = (key0 + 1 < VL) ? -2.0f * acc1.y : NEGV;

  // wave-level max per q-row, then cross-wave via LDS
  {
    float m0 = fmaxf(s0.x, s0.y);
    float m1 = fmaxf(s1.x, s1.y);
#pragma unroll
    for (int off = 32; off > 0; off >>= 1) {
      m0 = fmaxf(m0, __shfl_xor(m0, off));
      m1 = fmaxf(m1, __shfl_xor(m1, off));
    }
    if (lane == 0) { redm[w][0] = m0; redm[w][1] = m1; }
  }
  __syncthreads();
  float mg0 = redm[0][0], mg1 = redm[0][1];
#pragma unroll
  for (int ww = 1; ww < 8; ++ww) {
    mg0 = fmaxf(mg0, redm[ww][0]);
    mg1 = fmaxf(mg1, redm[ww][1]);
  }

  // exp + wave sum + cross-wave sum
  float2 p0, p1;
  p0.x = fast_exp2((s0.x - mg0) * LOG2E);
  p0.y = fast_exp2((s0.y - mg0) * LOG2E);
  p1.x = fast_exp2((s1.x - mg1) * LOG2E);
  p1.y = fast_exp2((s1.y - mg1) * LOG2E);
  {
    float t0 = p0.x + p0.y, t1 = p1.x + p1.y;
#pragma unroll
    for (int off = 32; off > 0; off >>= 1) {
      t0 += __shfl_xor(t0, off);
      t1 += __shfl_xor(t1, off);
    }
    if (lane == 0) { reds[w][0] = t0; reds[w][1] = t1; }
  }
  __syncthreads();
  float tot0 = reds[0][0], tot1 = reds[0][1];
#pragma unroll
  for (int ww = 1; ww < 8; ++ww) { tot0 += reds[ww][0]; tot1 += reds[ww][1]; }
  const float inv0 = fast_rcp(tot0);
  const float inv1 = fast_rcp(tot1);

  f16x2 h0, h1;
  h0[0] = (_Float16)(p0.x * inv0); h0[1] = (_Float16)(p0.y * inv0);
  h1[0] = (_Float16)(p1.x * inv1); h1[1] = (_Float16)(p1.y * inv1);
  *(f16x2*)&attnH[(size_t)(b * NLQ + qg * 2 + 0) * NLK + key0] = h0;
  *(f16x2*)&attnH[(size_t)(b * NLQ + qg * 2 + 1) * NLK + key0] = h1;
}

// ---------------------------------------------------------------------------
// PV via fp16 MFMA: out[b] = attn[b] (256x1024 fp16, row stride 1024) @ V[b].
// Block 256 thr = 4 waves; tile M64 x N64, K-step 32, register prefetch.
// ---------------------------------------------------------------------------
__global__ __launch_bounds__(256)
void pv_mfma_kernel(const _Float16* __restrict__ attnH, const float* __restrict__ V,
                    float* __restrict__ out) {
  const int b  = blockIdx.z;
  const int m0 = blockIdx.x * 64;
  const int n0 = blockIdx.y * 64;
  const int tid = threadIdx.x;
  const int w = tid >> 6, lane = tid & 63;

  __shared__ _Float16 aT[64][40];   // [m][k]
  __shared__ _Float16 vT[64][32];   // [n][k], swizzled

  const _Float16* aBase = attnH + (size_t)(b * NLQ + m0) * NLK;
  const float*    vBase = V + (size_t)b * NLK * NDV + n0;
  float*          oBase = out + (size_t)(b * NLQ + m0) * NDV + n0;

  const int ar = tid >> 2;               // 0..63
  const int ak = (tid & 3) * 8;          // 0,8,16,24
  const int vk = tid >> 4;               // 0..15
  const int vn = (tid & 15) * 4;         // 0..60
  const int vswz = ((vn >> 2) & 3) << 3;

  const int am  = w * 16 + (lane & 15);
  const int akf = (lane >> 4) * 8;
  const int bn  = lane & 15;
  const int bks = akf ^ (((bn >> 2) & 3) << 3);

  f32x4 acc0 = {}, acc1 = {}, acc2 = {}, acc3 = {};

  // prologue: prefetch tile 0 into registers
  f16x8 aReg = *(const f16x8*)&aBase[(size_t)ar * NLK + ak];
  float4 vReg0 = *(const float4*)&vBase[(size_t)(vk) * NDV + vn];
  float4 vReg1 = *(const float4*)&vBase[(size_t)(16 + vk) * NDV + vn];

  for (int k0 = 0; k0 < NLK; k0 += 32) {
    __syncthreads();   // previous tile's LDS reads complete
    *(f16x8*)&aT[ar][ak] = aReg;
    {
      const int ks0 = vk ^ vswz;
      vT[vn + 0][ks0] = (_Float16)vReg0.x;
      vT[vn + 1][ks0] = (_Float16)vReg0.y;
      vT[vn + 2][ks0] = (_Float16)vReg0.z;
      vT[vn + 3][ks0] = (_Float16)vReg0.w;
      const int ks1 = (16 + vk) ^ vswz;
      vT[vn + 0][ks1] = (_Float16)vReg1.x;
      vT[vn + 1][ks1] = (_Float16)vReg1.y;
      vT[vn + 2][ks1] = (_Float16)vReg1.z;
      vT[vn + 3][ks1] = (_Float16)vReg1.w;
    }
    __syncthreads();

    // prefetch NEXT tile while current MFMAs run
    if (k0 + 32 < NLK) {
      aReg = *(const f16x8*)&aBase[(size_t)ar * NLK + k0 + 32 + ak];
      vReg0 = *(const float4*)&vBase[(size_t)(k0 + 32 + vk) * NDV + vn];
      vReg1 = *(const float4*)&vBase[(size_t)(k0 + 48 + vk) * NDV + vn];
    }

    const f16x8 af = *(const f16x8*)&aT[am][akf];
    const f16x8 bf0 = *(const f16x8*)&vT[ 0 + bn][bks];
    const f16x8 bf1 = *(const f16x8*)&vT[16 + bn][bks];
    const f16x8 bf2 = *(const f16x8*)&vT[32 + bn][bks];
    const f16x8 bf3 = *(const f16x8*)&vT[48 + bn][bks];
    acc0 = __builtin_amdgcn_mfma_f32_16x16x32_f16(af, bf0, acc0, 0, 0, 0);
    acc1 = __builtin_amdgcn_mfma_f32_16x16x32_f16(af, bf1, acc1, 0, 0, 0);
    acc2 = __builtin_amdgcn_mfma_f32_16x16x32_f16(af, bf2, acc2, 0, 0, 0);
    acc3 = __builtin_amdgcn_mfma_f32_16x16x32_f16(af, bf3, acc3, 0, 0, 0);
  }

  const int orow = w * 16 + (lane >> 4) * 4;
  const int ocol = lane & 15;
#pragma unroll
  for (int r = 0; r < 4; ++r) {
    oBase[(size_t)(orow + r) * NDV + ocol +  0] = acc0[r];
    oBase[(size_t)(orow + r) * NDV + ocol + 16] = acc1[r];
    oBase[(size_t)(orow + r) * NDV + ocol + 32] = acc2[r];
    oBase[(size_t)(orow + r) * NDV + ocol + 48] = acc3[r];
  }
}

// ---------------------------------------------------------------------------
extern "C" void kernel_launch(void* const* d_in, const int* in_sizes, int n_in,
                              void* d_out, int out_size, void* d_ws, size_t ws_size,
                              hipStream_t stream) {
  const float* Q    = (const float*)d_in[0];
  const float* Kin  = (const float*)d_in[1];
  const float* V    = (const float*)d_in[2];
  const int*   vlen = (const int*)d_in[3];
  const float* Wq   = (const float*)d_in[4];
  const float* Wk   = (const float*)d_in[5];
  const float* wv   = (const float*)d_in[6];
  float* out = (float*)d_out;

  float* qp  = (float*)d_ws;                    // Eq: 2048*128 row-major
  float* ekT = qp + NBATCH * NLQ * NH;          // EkT: 8*128*1024
  _Float16* attnH = (_Float16*)(ekT + NBATCH * NH * NLK);       // 8*256*1024 fp16
  _Float16* wT = attnH + (size_t)NBATCH * NLQ * NLK;            // 2*128*512 fp16

  hipLaunchKernelGGL(prep_wT_kernel, dim3(2 * NDQ * NH / 256), dim3(256), 0, stream,
                     Wq, Wk, wT);
  hipLaunchKernelGGL(proj_mfma_kernel, dim3(160, 4), dim3(256), 0, stream,
                     Q, Kin, wT, qp, ekT);
  hipLaunchKernelGGL(scores_softmax_kernel, dim3(NBATCH, 128), dim3(512), 0, stream,
                     qp, ekT, wv, vlen, attnH);
  hipLaunchKernelGGL(pv_mfma_kernel, dim3(NLQ / 64, NDV / 64, NBATCH), dim3(256), 0, stream,
                     attnH, V, out);
}

// Round 15
// 77.157 us; speedup vs baseline: 1.1839x; 1.1839x over previous
//
#include <hip/hip_runtime.h>

// Problem constants
#define NBATCH 8
#define NLQ    256
#define NLK    1024
#define NDQ    512
#define NDV    512
#define NH     128
#define NEGV   -1000000.0f
#define TANH_SCALE 2.8853900817779268f   // 2*log2(e)
#define LOG2E      1.4426950408889634f

using f16x8 = __attribute__((ext_vector_type(8))) _Float16;
using f16x4 = __attribute__((ext_vector_type(4))) _Float16;
using f16x2 = __attribute__((ext_vector_type(2))) _Float16;
using f32x4 = __attribute__((ext_vector_type(4))) float;

__device__ __forceinline__ float fast_exp2(float x) {
#if __has_builtin(__builtin_amdgcn_exp2f)
  return __builtin_amdgcn_exp2f(x);
#else
  return exp2f(x);
#endif
}
__device__ __forceinline__ float fast_rcp(float x) {
#if __has_builtin(__builtin_amdgcn_rcpf)
  return __builtin_amdgcn_rcpf(x);
#else
  return 1.0f / x;
#endif
}

// ---------------------------------------------------------------------------
// Prep: WT fp16 [2][128][512]; WT[s][n][k] = W_s[k][n]. 256 KB, L2-resident.
// ---------------------------------------------------------------------------
__global__ __launch_bounds__(256)
void prep_wT_kernel(const float* __restrict__ Wq, const float* __restrict__ Wk,
                    _Float16* __restrict__ wT) {
  const int idx = blockIdx.x * 256 + threadIdx.x;   // 0 .. 2*512*128-1
  const int n = idx & 127;
  const int k = (idx >> 7) & 511;
  const int s = idx >> 16;
  const float* W = s ? Wk : Wq;
  wT[((size_t)(s * NH + n)) * NDQ + k] = (_Float16)W[k * NH + n];
}

// ---------------------------------------------------------------------------
// Projections via fp16 MFMA, LDS-FREE, barrier-free.
// Wave = 16 rows x 32 cols (2 frags of 16x16), block = 4 waves (64 rows).
// Grid (160, 4): bx<32 -> Q (M=2048), else K (M=8192); by = n-quarter.
// Epilogue: exp2(acc*2log2e); Q -> Eq row-major, K -> EkT[b][h][key].
// ---------------------------------------------------------------------------
__global__ __launch_bounds__(256)
void proj_mfma_kernel(const float* __restrict__ Q, const float* __restrict__ Kin,
                      const _Float16* __restrict__ wT,
                      float* __restrict__ qp, float* __restrict__ ekT) {
  const int bx = blockIdx.x;
  const int nq = blockIdx.y;          // n-quarter: cols nq*32 .. nq*32+31
  const bool isQ = (bx < 32);
  const float* A = isQ ? Q : Kin;
  const int m0 = (isQ ? bx : bx - 32) * 64;
  const int sIdx = isQ ? 0 : 1;

  const int w = threadIdx.x >> 6, lane = threadIdx.x & 63;
  const int mrow = m0 + w * 16 + (lane & 15);
  const int kseg = (lane >> 4) * 8;

  const float* aBase = A + (size_t)mrow * NDQ + kseg;
  const _Float16* wt0 = wT + ((size_t)(sIdx * NH + nq * 32 +      (lane & 15))) * NDQ + kseg;
  const _Float16* wt1 = wT + ((size_t)(sIdx * NH + nq * 32 + 16 + (lane & 15))) * NDQ + kseg;

  f32x4 acc0 = {}, acc1 = {};
#pragma unroll 4
  for (int k0 = 0; k0 < NDQ; k0 += 32) {
    const float4 a0 = *(const float4*)&aBase[k0];
    const float4 a1 = *(const float4*)&aBase[k0 + 4];
    f16x8 af;
    af[0] = (_Float16)a0.x; af[1] = (_Float16)a0.y;
    af[2] = (_Float16)a0.z; af[3] = (_Float16)a0.w;
    af[4] = (_Float16)a1.x; af[5] = (_Float16)a1.y;
    af[6] = (_Float16)a1.z; af[7] = (_Float16)a1.w;
    const f16x8 b0 = *(const f16x8*)&wt0[k0];
    const f16x8 b1 = *(const f16x8*)&wt1[k0];
    acc0 = __builtin_amdgcn_mfma_f32_16x16x32_f16(af, b0, acc0, 0, 0, 0);
    acc1 = __builtin_amdgcn_mfma_f32_16x16x32_f16(af, b1, acc1, 0, 0, 0);
  }

  const int orow = m0 + w * 16 + (lane >> 4) * 4;   // + r
  const int col0 = nq * 32 + (lane & 15);           // frag0 col; frag1 = +16
  if (isQ) {
#pragma unroll
    for (int r = 0; r < 4; ++r) {
      qp[(size_t)(orow + r) * NH + col0]      = fast_exp2(acc0[r] * TANH_SCALE);
      qp[(size_t)(orow + r) * NH + col0 + 16] = fast_exp2(acc1[r] * TANH_SCALE);
    }
  } else {
#pragma unroll
    for (int r = 0; r < 4; ++r) {
      const int grow = orow + r;
      const int b = grow >> 10, key = grow & 1023;
      ekT[((size_t)(b * NH) + col0)      * NLK + key] = fast_exp2(acc0[r] * TANH_SCALE);
      ekT[((size_t)(b * NH) + col0 + 16) * NLK + key] = fast_exp2(acc1[r] * TANH_SCALE);
    }
  }
}

// ---------------------------------------------------------------------------
// FUSED scores + masked softmax -> fp16 attn (R13 structure, proven 43us)
// + vlen-adaptive skip: a wave whose 128-key segment lies entirely beyond
// VL skips the g-loop (acc=0 -> masked to NEGV -> p=0, bit-identical output).
// E[VL]=512 -> ~half the score work skipped. Grid (64, NBATCH) UNPINNED:
// linear%8 = qg%8 mixes batches across XCDs so the max-VL batch doesn't
// dominate wall time (load-balance to mean VL).
//   score = Wsum - 2*sum_h w*rcp(1 + Eq*Ek); Wsum cancels in softmax.
// ---------------------------------------------------------------------------
__global__ __launch_bounds__(512)
void scores_softmax_kernel(const float* __restrict__ qp, const float* __restrict__ ekT,
                           const float* __restrict__ wv, const int* __restrict__ vlen,
                           _Float16* __restrict__ attnH) {
  const int qg = blockIdx.x;            // q group (4 rows), 0..63
  const int b  = blockIdx.y;            // batch
  const int w = threadIdx.x >> 6;       // 0..7 -> key segment of 128
  const int lane = threadIdx.x & 63;
  const int key0 = w * 128 + lane * 2;

  __shared__ float redm[8][4];
  __shared__ float reds[8][4];

  const float* kcol  = &ekT[(size_t)b * NH * NLK + key0];       // + h*NLK
  const float* qbase = &qp[(size_t)(b * NLQ + qg * 4) * NH];
  const int VL = vlen[b];

  float2 acc[4] = {};
  if (w * 128 < VL) {                   // wave-uniform: skip fully-masked segments
#pragma unroll 8
    for (int g = 0; g < 32; ++g) {
      const float4 w4 = *(const float4*)&wv[g * 4];               // uniform
      float4 q4[4];
#pragma unroll
      for (int qi = 0; qi < 4; ++qi)
        q4[qi] = *(const float4*)&qbase[qi * NH + g * 4];         // uniform
#pragma unroll
      for (int hh = 0; hh < 4; ++hh) {
        const float2 kv = *(const float2*)&kcol[(size_t)(g * 4 + hh) * NLK];
        const float wl = (hh == 0) ? w4.x : (hh == 1) ? w4.y : (hh == 2) ? w4.z : w4.w;
#pragma unroll
        for (int qi = 0; qi < 4; ++qi) {
          const float qs = (hh == 0) ? q4[qi].x : (hh == 1) ? q4[qi].y
                         : (hh == 2) ? q4[qi].z : q4[qi].w;
          acc[qi].x = fmaf(wl, fast_rcp(fmaf(qs, kv.x, 1.0f)), acc[qi].x);
          acc[qi].y = fmaf(wl, fast_rcp(fmaf(qs, kv.y, 1.0f)), acc[qi].y);
        }
      }
    }
  }

  // finalize scores with mask
  float2 s[4];
#pragma unroll
  for (int qi = 0; qi < 4; ++qi) {
    s[qi].x = (key0 + 0 < VL) ? -2.0f * acc[qi].x : NEGV;
    s[qi].y = (key0 + 1 < VL) ? -2.0f * acc[qi].y : NEGV;
  }

  // wave-level max per q-row, then cross-wave via LDS
#pragma unroll
  for (int qi = 0; qi < 4; ++qi) {
    float m = fmaxf(s[qi].x, s[qi].y);
#pragma unroll
    for (int off = 32; off > 0; off >>= 1) m = fmaxf(m, __shfl_xor(m, off));
    if (lane == 0) redm[w][qi] = m;
  }
  __syncthreads();
  float mg[4];
#pragma unroll
  for (int qi = 0; qi < 4; ++qi) {
    float m = redm[0][qi];
#pragma unroll
    for (int ww = 1; ww < 8; ++ww) m = fmaxf(m, redm[ww][qi]);
    mg[qi] = m;
  }

  // exp + wave sum + cross-wave sum
  float2 p[4];
#pragma unroll
  for (int qi = 0; qi < 4; ++qi) {
    p[qi].x = fast_exp2((s[qi].x - mg[qi]) * LOG2E);
    p[qi].y = fast_exp2((s[qi].y - mg[qi]) * LOG2E);
    float sum = p[qi].x + p[qi].y;
#pragma unroll
    for (int off = 32; off > 0; off >>= 1) sum += __shfl_xor(sum, off);
    if (lane == 0) reds[w][qi] = sum;
  }
  __syncthreads();

#pragma unroll
  for (int qi = 0; qi < 4; ++qi) {
    float tot = reds[0][qi];
#pragma unroll
    for (int ww = 1; ww < 8; ++ww) tot += reds[ww][qi];
    const float inv = fast_rcp(tot);
    f16x2 h;
    h[0] = (_Float16)(p[qi].x * inv);
    h[1] = (_Float16)(p[qi].y * inv);
    *(f16x2*)&attnH[(size_t)(b * NLQ + qg * 4 + qi) * NLK + key0] = h;
  }
}

// ---------------------------------------------------------------------------
// PV via fp16 MFMA: out[b] = attn[b] (256x1024 fp16) @ V[b].
// Block 256 thr = 4 waves; tile M64 x N64, K-step 32, register prefetch.
// vlen-adaptive: attn is exactly 0 for keys >= VL, so the K-loop stops at
// ceil(VL/32)*32 (expected ~half the MFMA + V traffic skipped).
// ---------------------------------------------------------------------------
__global__ __launch_bounds__(256)
void pv_mfma_kernel(const _Float16* __restrict__ attnH, const float* __restrict__ V,
                    const int* __restrict__ vlen, float* __restrict__ out) {
  const int b  = blockIdx.z;
  const int m0 = blockIdx.x * 64;
  const int n0 = blockIdx.y * 64;
  const int tid = threadIdx.x;
  const int w = tid >> 6, lane = tid & 63;
  const int kmax = (vlen[b] + 31) & ~31;   // ceil to K-step; >=32 since VL>=1

  __shared__ _Float16 aT[64][40];   // [m][k]
  __shared__ _Float16 vT[64][32];   // [n][k], swizzled

  const _Float16* aBase = attnH + (size_t)(b * NLQ + m0) * NLK;
  const float*    vBase = V + (size_t)b * NLK * NDV + n0;
  float*          oBase = out + (size_t)(b * NLQ + m0) * NDV + n0;

  const int ar = tid >> 2;               // 0..63
  const int ak = (tid & 3) * 8;          // 0,8,16,24
  const int vk = tid >> 4;               // 0..15
  const int vn = (tid & 15) * 4;         // 0..60
  const int vswz = ((vn >> 2) & 3) << 3;

  const int am  = w * 16 + (lane & 15);
  const int akf = (lane >> 4) * 8;
  const int bn  = lane & 15;
  const int bks = akf ^ (((bn >> 2) & 3) << 3);

  f32x4 acc0 = {}, acc1 = {}, acc2 = {}, acc3 = {};

  // prologue: prefetch tile 0 into registers
  f16x8 aReg = *(const f16x8*)&aBase[(size_t)ar * NLK + ak];
  float4 vReg0 = *(const float4*)&vBase[(size_t)(vk) * NDV + vn];
  float4 vReg1 = *(const float4*)&vBase[(size_t)(16 + vk) * NDV + vn];

  for (int k0 = 0; k0 < kmax; k0 += 32) {
    __syncthreads();   // previous tile's LDS reads complete
    *(f16x8*)&aT[ar][ak] = aReg;
    {
      const int ks0 = vk ^ vswz;
      vT[vn + 0][ks0] = (_Float16)vReg0.x;
      vT[vn + 1][ks0] = (_Float16)vReg0.y;
      vT[vn + 2][ks0] = (_Float16)vReg0.z;
      vT[vn + 3][ks0] = (_Float16)vReg0.w;
      const int ks1 = (16 + vk) ^ vswz;
      vT[vn + 0][ks1] = (_Float16)vReg1.x;
      vT[vn + 1][ks1] = (_Float16)vReg1.y;
      vT[vn + 2][ks1] = (_Float16)vReg1.z;
      vT[vn + 3][ks1] = (_Float16)vReg1.w;
    }
    __syncthreads();

    // prefetch NEXT tile while current MFMAs run
    if (k0 + 32 < kmax) {
      aReg = *(const f16x8*)&aBase[(size_t)ar * NLK + k0 + 32 + ak];
      vReg0 = *(const float4*)&vBase[(size_t)(k0 + 32 + vk) * NDV + vn];
      vReg1 = *(const float4*)&vBase[(size_t)(k0 + 48 + vk) * NDV + vn];
    }

    const f16x8 af = *(const f16x8*)&aT[am][akf];
    const f16x8 bf0 = *(const f16x8*)&vT[ 0 + bn][bks];
    const f16x8 bf1 = *(const f16x8*)&vT[16 + bn][bks];
    const f16x8 bf2 = *(const f16x8*)&vT[32 + bn][bks];
    const f16x8 bf3 = *(const f16x8*)&vT[48 + bn][bks];
    acc0 = __builtin_amdgcn_mfma_f32_16x16x32_f16(af, bf0, acc0, 0, 0, 0);
    acc1 = __builtin_amdgcn_mfma_f32_16x16x32_f16(af, bf1, acc1, 0, 0, 0);
    acc2 = __builtin_amdgcn_mfma_f32_16x16x32_f16(af, bf2, acc2, 0, 0, 0);
    acc3 = __builtin_amdgcn_mfma_f32_16x16x32_f16(af, bf3, acc3, 0, 0, 0);
  }

  const int orow = w * 16 + (lane >> 4) * 4;
  const int ocol = lane & 15;
#pragma unroll
  for (int r = 0; r < 4; ++r) {
    oBase[(size_t)(orow + r) * NDV + ocol +  0] = acc0[r];
    oBase[(size_t)(orow + r) * NDV + ocol + 16] = acc1[r];
    oBase[(size_t)(orow + r) * NDV + ocol + 32] = acc2[r];
    oBase[(size_t)(orow + r) * NDV + ocol + 48] = acc3[r];
  }
}

// ---------------------------------------------------------------------------
extern "C" void kernel_launch(void* const* d_in, const int* in_sizes, int n_in,
                              void* d_out, int out_size, void* d_ws, size_t ws_size,
                              hipStream_t stream) {
  const float* Q    = (const float*)d_in[0];
  const float* Kin  = (const float*)d_in[1];
  const float* V    = (const float*)d_in[2];
  const int*   vlen = (const int*)d_in[3];
  const float* Wq   = (const float*)d_in[4];
  const float* Wk   = (const float*)d_in[5];
  const float* wv   = (const float*)d_in[6];
  float* out = (float*)d_out;

  float* qp  = (float*)d_ws;                    // Eq: 2048*128 row-major
  float* ekT = qp + NBATCH * NLQ * NH;          // EkT: 8*128*1024
  _Float16* attnH = (_Float16*)(ekT + NBATCH * NH * NLK);       // 8*256*1024 fp16
  _Float16* wT = attnH + (size_t)NBATCH * NLQ * NLK;            // 2*128*512 fp16

  hipLaunchKernelGGL(prep_wT_kernel, dim3(2 * NDQ * NH / 256), dim3(256), 0, stream,
                     Wq, Wk, wT);
  hipLaunchKernelGGL(proj_mfma_kernel, dim3(160, 4), dim3(256), 0, stream,
                     Q, Kin, wT, qp, ekT);
  hipLaunchKernelGGL(scores_softmax_kernel, dim3(64, NBATCH), dim3(512), 0, stream,
                     qp, ekT, wv, vlen, attnH);
  hipLaunchKernelGGL(pv_mfma_kernel, dim3(NLQ / 64, NDV / 64, NBATCH), dim3(256), 0, stream,
                     attnH, V, vlen, out);
}

// Round 16
// 75.274 us; speedup vs baseline: 1.2135x; 1.0250x over previous
//
#include <hip/hip_runtime.h>

// Problem constants
#define NBATCH 8
#define NLQ    256
#define NLK    1024
#define NDQ    512
#define NDV    512
#define NH     128
#define NEGV   -1000000.0f
#define TANH_SCALE 2.8853900817779268f   // 2*log2(e)
#define LOG2E      1.4426950408889634f

using f16x8 = __attribute__((ext_vector_type(8))) _Float16;
using f16x4 = __attribute__((ext_vector_type(4))) _Float16;
using f16x2 = __attribute__((ext_vector_type(2))) _Float16;
using f32x4 = __attribute__((ext_vector_type(4))) float;

__device__ __forceinline__ float fast_exp2(float x) {
#if __has_builtin(__builtin_amdgcn_exp2f)
  return __builtin_amdgcn_exp2f(x);
#else
  return exp2f(x);
#endif
}
__device__ __forceinline__ float fast_rcp(float x) {
#if __has_builtin(__builtin_amdgcn_rcpf)
  return __builtin_amdgcn_rcpf(x);
#else
  return 1.0f / x;
#endif
}

// ---------------------------------------------------------------------------
// Prep: WT fp16 [2][128][512]; WT[s][n][k] = W_s[k][n]. 256 KB, L2-resident.
// ---------------------------------------------------------------------------
__global__ __launch_bounds__(256)
void prep_wT_kernel(const float* __restrict__ Wq, const float* __restrict__ Wk,
                    _Float16* __restrict__ wT) {
  const int idx = blockIdx.x * 256 + threadIdx.x;   // 0 .. 2*512*128-1
  const int n = idx & 127;
  const int k = (idx >> 7) & 511;
  const int s = idx >> 16;
  const float* W = s ? Wk : Wq;
  wT[((size_t)(s * NH + n)) * NDQ + k] = (_Float16)W[k * NH + n];
}

// ---------------------------------------------------------------------------
// Projections via fp16 MFMA, LDS-FREE, barrier-free.
// Wave = 16 rows x 32 cols (2 frags of 16x16), block = 4 waves (64 rows).
// Grid (160, 4): bx<32 -> Q (M=2048), else K (M=8192); by = n-quarter.
// vlen-skip: K-blocks whose 64 keys all lie >= vlen[b] return immediately
// (their Ek is only ever read by scores lanes that get masked to NEGV).
// Epilogue: exp2(acc*2log2e); Q -> Eq row-major, K -> EkT[b][h][key].
// ---------------------------------------------------------------------------
__global__ __launch_bounds__(256)
void proj_mfma_kernel(const float* __restrict__ Q, const float* __restrict__ Kin,
                      const _Float16* __restrict__ wT, const int* __restrict__ vlen,
                      float* __restrict__ qp, float* __restrict__ ekT) {
  const int bx = blockIdx.x;
  const int nq = blockIdx.y;          // n-quarter: cols nq*32 .. nq*32+31
  const bool isQ = (bx < 32);
  const float* A = isQ ? Q : Kin;
  const int m0 = (isQ ? bx : bx - 32) * 64;
  const int sIdx = isQ ? 0 : 1;

  if (!isQ) {
    const int b = m0 >> 10;
    if ((m0 & 1023) >= vlen[b]) return;   // dead keys: never consumed unmasked
  }

  const int w = threadIdx.x >> 6, lane = threadIdx.x & 63;
  const int mrow = m0 + w * 16 + (lane & 15);
  const int kseg = (lane >> 4) * 8;

  const float* aBase = A + (size_t)mrow * NDQ + kseg;
  const _Float16* wt0 = wT + ((size_t)(sIdx * NH + nq * 32 +      (lane & 15))) * NDQ + kseg;
  const _Float16* wt1 = wT + ((size_t)(sIdx * NH + nq * 32 + 16 + (lane & 15))) * NDQ + kseg;

  f32x4 acc0 = {}, acc1 = {};
#pragma unroll 4
  for (int k0 = 0; k0 < NDQ; k0 += 32) {
    const float4 a0 = *(const float4*)&aBase[k0];
    const float4 a1 = *(const float4*)&aBase[k0 + 4];
    f16x8 af;
    af[0] = (_Float16)a0.x; af[1] = (_Float16)a0.y;
    af[2] = (_Float16)a0.z; af[3] = (_Float16)a0.w;
    af[4] = (_Float16)a1.x; af[5] = (_Float16)a1.y;
    af[6] = (_Float16)a1.z; af[7] = (_Float16)a1.w;
    const f16x8 b0 = *(const f16x8*)&wt0[k0];
    const f16x8 b1 = *(const f16x8*)&wt1[k0];
    acc0 = __builtin_amdgcn_mfma_f32_16x16x32_f16(af, b0, acc0, 0, 0, 0);
    acc1 = __builtin_amdgcn_mfma_f32_16x16x32_f16(af, b1, acc1, 0, 0, 0);
  }

  const int orow = m0 + w * 16 + (lane >> 4) * 4;   // + r
  const int col0 = nq * 32 + (lane & 15);           // frag0 col; frag1 = +16
  if (isQ) {
#pragma unroll
    for (int r = 0; r < 4; ++r) {
      qp[(size_t)(orow + r) * NH + col0]      = fast_exp2(acc0[r] * TANH_SCALE);
      qp[(size_t)(orow + r) * NH + col0 + 16] = fast_exp2(acc1[r] * TANH_SCALE);
    }
  } else {
#pragma unroll
    for (int r = 0; r < 4; ++r) {
      const int grow = orow + r;
      const int b = grow >> 10, key = grow & 1023;
      ekT[((size_t)(b * NH) + col0)      * NLK + key] = fast_exp2(acc0[r] * TANH_SCALE);
      ekT[((size_t)(b * NH) + col0 + 16) * NLK + key] = fast_exp2(acc1[r] * TANH_SCALE);
    }
  }
}

// ---------------------------------------------------------------------------
// FUSED scores + masked softmax -> fp16 attn (R13 structure) + vlen skip:
// a wave whose 128-key segment lies entirely beyond VL skips the g-loop
// (acc=0 -> masked to NEGV -> p=0, bit-identical output). Grid (64, NBATCH).
//   score = Wsum - 2*sum_h w*rcp(1 + Eq*Ek); Wsum cancels in softmax.
// ---------------------------------------------------------------------------
__global__ __launch_bounds__(512)
void scores_softmax_kernel(const float* __restrict__ qp, const float* __restrict__ ekT,
                           const float* __restrict__ wv, const int* __restrict__ vlen,
                           _Float16* __restrict__ attnH) {
  const int qg = blockIdx.x;            // q group (4 rows), 0..63
  const int b  = blockIdx.y;            // batch
  const int w = threadIdx.x >> 6;       // 0..7 -> key segment of 128
  const int lane = threadIdx.x & 63;
  const int key0 = w * 128 + lane * 2;

  __shared__ float redm[8][4];
  __shared__ float reds[8][4];

  const float* kcol  = &ekT[(size_t)b * NH * NLK + key0];       // + h*NLK
  const float* qbase = &qp[(size_t)(b * NLQ + qg * 4) * NH];
  const int VL = vlen[b];

  float2 acc[4] = {};
  if (w * 128 < VL) {                   // wave-uniform: skip fully-masked segments
#pragma unroll 8
    for (int g = 0; g < 32; ++g) {
      const float4 w4 = *(const float4*)&wv[g * 4];               // uniform
      float4 q4[4];
#pragma unroll
      for (int qi = 0; qi < 4; ++qi)
        q4[qi] = *(const float4*)&qbase[qi * NH + g * 4];         // uniform
#pragma unroll
      for (int hh = 0; hh < 4; ++hh) {
        const float2 kv = *(const float2*)&kcol[(size_t)(g * 4 + hh) * NLK];
        const float wl = (hh == 0) ? w4.x : (hh == 1) ? w4.y : (hh == 2) ? w4.z : w4.w;
#pragma unroll
        for (int qi = 0; qi < 4; ++qi) {
          const float qs = (hh == 0) ? q4[qi].x : (hh == 1) ? q4[qi].y
                         : (hh == 2) ? q4[qi].z : q4[qi].w;
          acc[qi].x = fmaf(wl, fast_rcp(fmaf(qs, kv.x, 1.0f)), acc[qi].x);
          acc[qi].y = fmaf(wl, fast_rcp(fmaf(qs, kv.y, 1.0f)), acc[qi].y);
        }
      }
    }
  }

  // finalize scores with mask
  float2 s[4];
#pragma unroll
  for (int qi = 0; qi < 4; ++qi) {
    s[qi].x = (key0 + 0 < VL) ? -2.0f * acc[qi].x : NEGV;
    s[qi].y = (key0 + 1 < VL) ? -2.0f * acc[qi].y : NEGV;
  }

  // wave-level max per q-row, then cross-wave via LDS
#pragma unroll
  for (int qi = 0; qi < 4; ++qi) {
    float m = fmaxf(s[qi].x, s[qi].y);
#pragma unroll
    for (int off = 32; off > 0; off >>= 1) m = fmaxf(m, __shfl_xor(m, off));
    if (lane == 0) redm[w][qi] = m;
  }
  __syncthreads();
  float mg[4];
#pragma unroll
  for (int qi = 0; qi < 4; ++qi) {
    float m = redm[0][qi];
#pragma unroll
    for (int ww = 1; ww < 8; ++ww) m = fmaxf(m, redm[ww][qi]);
    mg[qi] = m;
  }

  // exp + wave sum + cross-wave sum
  float2 p[4];
#pragma unroll
  for (int qi = 0; qi < 4; ++qi) {
    p[qi].x = fast_exp2((s[qi].x - mg[qi]) * LOG2E);
    p[qi].y = fast_exp2((s[qi].y - mg[qi]) * LOG2E);
    float sum = p[qi].x + p[qi].y;
#pragma unroll
    for (int off = 32; off > 0; off >>= 1) sum += __shfl_xor(sum, off);
    if (lane == 0) reds[w][qi] = sum;
  }
  __syncthreads();

#pragma unroll
  for (int qi = 0; qi < 4; ++qi) {
    float tot = reds[0][qi];
#pragma unroll
    for (int ww = 1; ww < 8; ++ww) tot += reds[ww][qi];
    const float inv = fast_rcp(tot);
    f16x2 h;
    h[0] = (_Float16)(p[qi].x * inv);
    h[1] = (_Float16)(p[qi].y * inv);
    *(f16x2*)&attnH[(size_t)(b * NLQ + qg * 4 + qi) * NLK + key0] = h;
  }
}

// ---------------------------------------------------------------------------
// PV via fp16 MFMA: out[b] = attn[b] (256x1024 fp16) @ V[b].
// Tile M64 x N32 -> grid (4,16,8) = 512 blocks = 2 blocks/CU (2x occupancy
// vs 64x64). Block 256 thr = 4 waves; wave = 16 rows x 32 cols (2 frags).
// K-step 32, register prefetch. vlen-adaptive: attn==0 for keys>=VL, K-loop
// stops at ceil(VL/32)*32.
// ---------------------------------------------------------------------------
__global__ __launch_bounds__(256)
void pv_mfma_kernel(const _Float16* __restrict__ attnH, const float* __restrict__ V,
                    const int* __restrict__ vlen, float* __restrict__ out) {
  const int b  = blockIdx.z;
  const int m0 = blockIdx.x * 64;
  const int n0 = blockIdx.y * 32;
  const int tid = threadIdx.x;
  const int w = tid >> 6, lane = tid & 63;
  const int kmax = (vlen[b] + 31) & ~31;   // ceil to K-step; >=32 since VL>=1

  __shared__ _Float16 aT[64][40];   // [m][k]
  __shared__ _Float16 vT[32][32];   // [n][k], swizzled

  const _Float16* aBase = attnH + (size_t)(b * NLQ + m0) * NLK;
  const float*    vBase = V + (size_t)b * NLK * NDV + n0;
  float*          oBase = out + (size_t)(b * NLQ + m0) * NDV + n0;

  const int ar = tid >> 2;               // 0..63
  const int ak = (tid & 3) * 8;          // 0,8,16,24
  const int vk = tid >> 3;               // 0..31 (k within tile)
  const int vn = (tid & 7) * 4;          // 0..28 (n within tile)
  const int vswz = ((vn >> 2) & 3) << 3;

  const int am  = w * 16 + (lane & 15);
  const int akf = (lane >> 4) * 8;
  const int bn  = lane & 15;
  const int bks = akf ^ (((bn >> 2) & 3) << 3);

  f32x4 acc0 = {}, acc1 = {};

  // prologue: prefetch tile 0 into registers
  f16x8 aReg = *(const f16x8*)&aBase[(size_t)ar * NLK + ak];
  float4 vReg = *(const float4*)&vBase[(size_t)vk * NDV + vn];

  for (int k0 = 0; k0 < kmax; k0 += 32) {
    __syncthreads();   // previous tile's LDS reads complete
    *(f16x8*)&aT[ar][ak] = aReg;
    {
      const int ks = vk ^ vswz;
      vT[vn + 0][ks] = (_Float16)vReg.x;
      vT[vn + 1][ks] = (_Float16)vReg.y;
      vT[vn + 2][ks] = (_Float16)vReg.z;
      vT[vn + 3][ks] = (_Float16)vReg.w;
    }
    __syncthreads();

    // prefetch NEXT tile while current MFMAs run
    if (k0 + 32 < kmax) {
      aReg = *(const f16x8*)&aBase[(size_t)ar * NLK + k0 + 32 + ak];
      vReg = *(const float4*)&vBase[(size_t)(k0 + 32 + vk) * NDV + vn];
    }

    const f16x8 af = *(const f16x8*)&aT[am][akf];
    const f16x8 bf0 = *(const f16x8*)&vT[ 0 + bn][bks];
    const f16x8 bf1 = *(const f16x8*)&vT[16 + bn][bks];
    acc0 = __builtin_amdgcn_mfma_f32_16x16x32_f16(af, bf0, acc0, 0, 0, 0);
    acc1 = __builtin_amdgcn_mfma_f32_16x16x32_f16(af, bf1, acc1, 0, 0, 0);
  }

  const int orow = w * 16 + (lane >> 4) * 4;
  const int ocol = lane & 15;
#pragma unroll
  for (int r = 0; r < 4; ++r) {
    oBase[(size_t)(orow + r) * NDV + ocol +  0] = acc0[r];
    oBase[(size_t)(orow + r) * NDV + ocol + 16] = acc1[r];
  }
}

// ---------------------------------------------------------------------------
extern "C" void kernel_launch(void* const* d_in, const int* in_sizes, int n_in,
                              void* d_out, int out_size, void* d_ws, size_t ws_size,
                              hipStream_t stream) {
  const float* Q    = (const float*)d_in[0];
  const float* Kin  = (const float*)d_in[1];
  const float* V    = (const float*)d_in[2];
  const int*   vlen = (const int*)d_in[3];
  const float* Wq   = (const float*)d_in[4];
  const float* Wk   = (const float*)d_in[5];
  const float* wv   = (const float*)d_in[6];
  float* out = (float*)d_out;

  float* qp  = (float*)d_ws;                    // Eq: 2048*128 row-major
  float* ekT = qp + NBATCH * NLQ * NH;          // EkT: 8*128*1024
  _Float16* attnH = (_Float16*)(ekT + NBATCH * NH * NLK);       // 8*256*1024 fp16
  _Float16* wT = attnH + (size_t)NBATCH * NLQ * NLK;            // 2*128*512 fp16

  hipLaunchKernelGGL(prep_wT_kernel, dim3(2 * NDQ * NH / 256), dim3(256), 0, stream,
                     Wq, Wk, wT);
  hipLaunchKernelGGL(proj_mfma_kernel, dim3(160, 4), dim3(256), 0, stream,
                     Q, Kin, wT, vlen, qp, ekT);
  hipLaunchKernelGGL(scores_softmax_kernel, dim3(64, NBATCH), dim3(512), 0, stream,
                     qp, ekT, wv, vlen, attnH);
  hipLaunchKernelGGL(pv_mfma_kernel, dim3(NLQ / 64, NDV / 32, NBATCH), dim3(256), 0, stream,
                     attnH, V, vlen, out);
}